// Round 9
// baseline (3058.593 us; speedup 1.0000x reference)
//
#include <hip/hip_runtime.h>
#include <stdint.h>

typedef float4 __attribute__((may_alias)) float4a;
typedef unsigned int u32;
typedef unsigned short u16;
typedef unsigned long long u64;
typedef __bf16 bf16x8 __attribute__((ext_vector_type(8)));
typedef float f32x4 __attribute__((ext_vector_type(4)));

// ws float layout: [0] loss, [1] sum(ema_cs),
// [16,+K) e2 | [16+K,+K) counts | [16+2K,+K*64) emb | [16+2K+KD,+N) win (u32)
#define WS_LOSS 0
#define WS_SEMA 1
#define WS_HDR  16
#define MARGIN  8e-5f   // > 2.2x hard bound 2(ulp(z2)+eps_mfma) ~= 3.6e-5

__global__ void k_sig(float* o, float v) { o[0] = v; }

__device__ __forceinline__ float bf2f(u32 u) { return __uint_as_float(u << 16); }
__device__ __forceinline__ u32 f2bf(float x) {
  u32 u = __float_as_uint(x);
  return (u + 0x7FFFu + ((u >> 16) & 1u)) >> 16;   // RNE
}
__device__ __forceinline__ float sq_nofuse(float x) {
  float p = x * x;
  __asm__("" : "+v"(p));   // block contraction: numpy rounds the square separately
  return p;
}
// numpy pairwise_sum, n=64: 8 accumulators + fixed combine tree (bit-exact)
__device__ __forceinline__ float np_pairwise64(const float* t) {
  float r0 = t[0], r1 = t[1], r2 = t[2], r3 = t[3];
  float r4 = t[4], r5 = t[5], r6 = t[6], r7 = t[7];
  #pragma unroll
  for (int i = 8; i < 64; i += 8) {
    r0 += t[i + 0]; r1 += t[i + 1]; r2 += t[i + 2]; r3 += t[i + 3];
    r4 += t[i + 4]; r5 += t[i + 5]; r6 += t[i + 6]; r7 += t[i + 7];
  }
  return ((r0 + r1) + (r2 + r3)) + ((r4 + r5) + (r6 + r7));
}

__global__ __launch_bounds__(256) void k_prep(const float* __restrict__ cb,
                                              const float* __restrict__ ecs,
                                              float* __restrict__ ws, int K) {
  const int k = blockIdx.x * 256 + threadIdx.x;
  const float* e = cb + ((size_t)k << 6);
  float t[64];
  #pragma unroll
  for (int j = 0; j < 64; ++j) t[j] = sq_nofuse(e[j]);
  ws[WS_HDR + k] = np_pairwise64(t);              // np-exact ||e||^2

  float v = ecs[k];
  #pragma unroll
  for (int o = 32; o; o >>= 1) v += __shfl_xor(v, o, 64);
  if ((threadIdx.x & 63) == 0) atomicAdd(&ws[WS_SEMA], v);
}

// pack codebook into MFMA B-fragment order, bf16 hi/lo split of e.
// esp uint4 index: (tile*4 + f)*64 + lane ; f: 0=eh k0-31, 1=eh k32-63, 2=el lo, 3=el hi
__global__ __launch_bounds__(256) void k_esplit(const float* __restrict__ cb,
                                                uint4* __restrict__ esp) {
  const int gid = blockIdx.x * 256 + threadIdx.x;   // K*8 threads
  const int n = gid >> 3, oct = gid & 7;
  const float* src = cb + ((size_t)n << 6) + oct * 8;
  const int t = n >> 4;
  const int fhi = (oct < 4) ? 0 : 1;
  const int lane = ((oct & 3) << 4) | (n & 15);
  u32 h[8], l[8];
  #pragma unroll
  for (int m = 0; m < 8; ++m) {
    const float x = src[m];
    h[m] = f2bf(x);
    l[m] = f2bf(x - bf2f(h[m]));
  }
  uint4 vh, vl;
  vh.x = h[0] | (h[1] << 16); vh.y = h[2] | (h[3] << 16);
  vh.z = h[4] | (h[5] << 16); vh.w = h[6] | (h[7] << 16);
  vl.x = l[0] | (l[1] << 16); vl.y = l[2] | (l[3] << 16);
  vl.z = l[4] | (l[5] << 16); vl.w = l[6] | (l[7] << 16);
  esp[(t * 4 + fhi) * 64 + lane] = vh;
  esp[(t * 4 + fhi + 2) * 64 + lane] = vl;
}

// MFMA distance scan: wave = 16 z-rows (A, regs), stream B-tiles via LDS.
// acc = e2 + 0.5 - 2 z.e ; per-lane packed top-2; flagged rows -> exact cleanup.
__global__ __launch_bounds__(256) void k_main(const float* __restrict__ z,
                                              const uint4* __restrict__ esp,
                                              const float* __restrict__ e2s,
                                              u32* __restrict__ win,
                                              int N, int K) {
  __shared__ uint4 sb[2][1024];    // 2 x 16 KB : supertile = 4 n-tiles (64 cb rows)
  __shared__ float se2[2][64];

  const int tid = threadIdx.x;
  const int lane = tid & 63;
  const int wv = tid >> 6;
  const int m = lane & 15;
  const int quad = lane >> 4;
  const int rowbase = blockIdx.x * 64 + wv * 16;

  // A-frags: -2z split; A[m=lane&15][k=quad*8+j] (+32 for frag1)
  bf16x8 ah0, ah1, al0, al1;
  {
    const float* zr = z + (((size_t)(rowbase + m)) << 6) + (quad << 3);
    union { u16 s[8]; bf16x8 v; } h0, h1, l0, l1;
    #pragma unroll
    for (int j = 0; j < 8; ++j) {
      const float x0 = -2.0f * zr[j];
      const u32 b0 = f2bf(x0);
      h0.s[j] = (u16)b0; l0.s[j] = (u16)f2bf(x0 - bf2f(b0));
      const float x1 = -2.0f * zr[j + 32];
      const u32 b1 = f2bf(x1);
      h1.s[j] = (u16)b1; l1.s[j] = (u16)f2bf(x1 - bf2f(b1));
    }
    ah0 = h0.v; ah1 = h1.v; al0 = l0.v; al1 = l1.v;
  }

  u64 t1[4] = {~0ull, ~0ull, ~0ull, ~0ull};
  u64 t2[4] = {~0ull, ~0ull, ~0ull, ~0ull};
  const int nst = K >> 6;

  { // prestage supertile 0
    sb[0][tid] = esp[tid];           sb[0][tid + 256] = esp[tid + 256];
    sb[0][tid + 512] = esp[tid + 512]; sb[0][tid + 768] = esp[tid + 768];
    if (tid < 64) se2[0][tid] = e2s[tid];
  }

  for (int st = 0; st < nst; ++st) {
    const int b = st & 1;
    __syncthreads();

    uint4 s0 = {}, s1 = {}, s2 = {}, s3 = {};
    float e2r = 0.f;
    const bool hn = (st + 1 < nst);
    if (hn) {
      const uint4* src = esp + (size_t)(st + 1) * 1024;
      s0 = src[tid]; s1 = src[tid + 256]; s2 = src[tid + 512]; s3 = src[tid + 768];
      if (tid < 64) e2r = e2s[(st + 1) * 64 + tid];
    }

    #pragma unroll
    for (int ti = 0; ti < 4; ++ti) {
      const uint4* fb = &sb[b][ti * 256];
      union { uint4 u; bf16x8 v; } bh0, bh1, bl0, bl1;
      bh0.u = fb[lane]; bh1.u = fb[64 + lane];
      bl0.u = fb[128 + lane]; bl1.u = fb[192 + lane];
      const float e2c = se2[b][ti * 16 + m] + 0.5f;   // bias keeps s>0 (u64-monotone)
      f32x4 acc = {e2c, e2c, e2c, e2c};
      acc = __builtin_amdgcn_mfma_f32_16x16x32_bf16(ah0, bh0.v, acc, 0, 0, 0);
      acc = __builtin_amdgcn_mfma_f32_16x16x32_bf16(ah1, bh1.v, acc, 0, 0, 0);
      acc = __builtin_amdgcn_mfma_f32_16x16x32_bf16(ah0, bl0.v, acc, 0, 0, 0);
      acc = __builtin_amdgcn_mfma_f32_16x16x32_bf16(ah1, bl1.v, acc, 0, 0, 0);
      acc = __builtin_amdgcn_mfma_f32_16x16x32_bf16(al0, bh0.v, acc, 0, 0, 0);
      acc = __builtin_amdgcn_mfma_f32_16x16x32_bf16(al1, bh1.v, acc, 0, 0, 0);
      const u32 kc = (u32)(st * 64 + ti * 16 + m);
      #pragma unroll
      for (int rg = 0; rg < 4; ++rg) {   // packed branchless top-2, k ascending
        const u64 key = ((u64)__float_as_uint(acc[rg]) << 32) | kc;
        const bool lt = key < t1[rg];
        const u64 hi = lt ? t1[rg] : key;
        t1[rg] = lt ? key : t1[rg];
        t2[rg] = (hi < t2[rg]) ? hi : t2[rg];
      }
    }

    if (hn) {
      sb[b ^ 1][tid] = s0;           sb[b ^ 1][tid + 256] = s1;
      sb[b ^ 1][tid + 512] = s2;     sb[b ^ 1][tid + 768] = s3;
      if (tid < 64) se2[b ^ 1][tid] = e2r;
    }
  }

  // merge top-2 across the 16 lanes sharing each row group
  #pragma unroll
  for (int s = 1; s < 16; s <<= 1) {
    #pragma unroll
    for (int rg = 0; rg < 4; ++rg) {
      const u64 o1 = __shfl_xor(t1[rg], s, 64);
      const u64 o2 = __shfl_xor(t2[rg], s, 64);
      const bool lt = t1[rg] < o1;
      const u64 n1 = lt ? t1[rg] : o1;
      const u64 hi = lt ? o1 : t1[rg];
      const u64 lo = (t2[rg] < o2) ? t2[rg] : o2;
      t2[rg] = (hi < lo) ? hi : lo;
      t1[rg] = n1;
    }
  }
  if (m < 4) {   // writer lane per (quad,reg): row = rowbase + quad*4 + reg
    u64 a = t1[0], c = t2[0];
    if (m == 1) { a = t1[1]; c = t2[1]; }
    if (m == 2) { a = t1[2]; c = t2[2]; }
    if (m == 3) { a = t1[3]; c = t2[3]; }
    const float f1 = __uint_as_float((u32)(a >> 32));
    const float f2 = __uint_as_float((u32)(c >> 32));
    u32 w = (u32)a;
    if (f2 - f1 < MARGIN) w |= 0x80000000u;     // ambiguous -> exact cleanup
    win[rowbase + quad * 4 + m] = w;
  }
}

// exact np-fp32 re-scan of flagged rows (wave per row, bit-exact round-6 chain)
__global__ __launch_bounds__(256) void k_clean(const float* __restrict__ z,
                                               const float* __restrict__ cb,
                                               const float* __restrict__ e2s,
                                               u32* __restrict__ win, int N, int K) {
  const int tid = threadIdx.x, lane = tid & 63, wv = tid >> 6;
  const int wbase = blockIdx.x * 64 + wv * 16;
  const u32 w0 = (lane < 16) ? win[wbase + lane] : 0u;
  u64 mask = __ballot((w0 & 0x80000000u) != 0u);
  while (mask) {
    const int bpos = __builtin_ctzll(mask);
    mask &= mask - 1;
    const int r = wbase + bpos;
    const float* zr = z + ((size_t)r << 6);
    float zv[64];
    #pragma unroll
    for (int t = 0; t < 16; ++t) {
      const float4 q = ((const float4a*)zr)[t];
      zv[4*t] = q.x; zv[4*t+1] = q.y; zv[4*t+2] = q.z; zv[4*t+3] = q.w;
    }
    float z2;
    {
      float t[64];
      #pragma unroll
      for (int j = 0; j < 64; ++j) t[j] = sq_nofuse(zv[j]);
      z2 = np_pairwise64(t);
    }
    u64 best = ~0ull;
    for (int t = 0; t < K / 64; ++t) {
      const int k = t * 64 + lane;
      const float* e = cb + ((size_t)k << 6);
      float g = 0.f;
      #pragma unroll
      for (int j = 0; j < 64; ++j) g = __builtin_fmaf(e[j], zv[j], g);
      const float wq = z2 + e2s[k];
      const float d = __builtin_fmaf(-2.0f, g, wq);   // == np's fl(t1 - 2g), d>0
      const u64 key = ((u64)__float_as_uint(d) << 32) | (u32)k;
      best = (key < best) ? key : best;
    }
    #pragma unroll
    for (int s = 32; s; s >>= 1) {
      const u64 o = __shfl_xor(best, s, 64);
      best = (o < best) ? o : best;
    }
    if (lane == 0) win[r] = (u32)best;   // clears flag bit
  }
}

// epilogue: index + quantized + loss + EMA scatter (coalesced row atomics)
__global__ __launch_bounds__(256) void k_post(const float* __restrict__ z,
                                              const float* __restrict__ cb,
                                              const u32* __restrict__ win,
                                              float* __restrict__ ws,
                                              float* __restrict__ o,
                                              int N, int K) {
  __shared__ float zt[256 * 65];
  __shared__ u32 bkb[256];
  const int tid = threadIdx.x;
  const int r = blockIdx.x * 256 + tid;
  const u32 bk = win[r] & 0x7FFFFFFFu;
  bkb[tid] = bk;
  const size_t base = (size_t)N << 6;
  o[base + 1 + (size_t)r] = (float)bk;

  const float4a* zr = (const float4a*)(z + ((size_t)r << 6));
  const float4a* qr = (const float4a*)(cb + ((size_t)bk << 6));
  float4a* dst = (float4a*)(o + ((size_t)r << 6));
  float lsum = 0.f;
  #pragma unroll
  for (int t = 0; t < 16; ++t) {
    const float4 zw = zr[t], qw = qr[t];
    float4 out; float d;
    d = zw.x - qw.x; lsum = __builtin_fmaf(d, d, lsum); out.x = zw.x + (qw.x - zw.x);
    d = zw.y - qw.y; lsum = __builtin_fmaf(d, d, lsum); out.y = zw.y + (qw.y - zw.y);
    d = zw.z - qw.z; lsum = __builtin_fmaf(d, d, lsum); out.z = zw.z + (qw.z - zw.z);
    d = zw.w - qw.w; lsum = __builtin_fmaf(d, d, lsum); out.w = zw.w + (qw.w - zw.w);
    dst[t] = out;
    zt[tid * 65 + 4*t]     = zw.x; zt[tid * 65 + 4*t + 1] = zw.y;
    zt[tid * 65 + 4*t + 2] = zw.z; zt[tid * 65 + 4*t + 3] = zw.w;
  }
  #pragma unroll
  for (int s = 32; s; s >>= 1) lsum += __shfl_xor(lsum, s, 64);
  if ((tid & 63) == 0) atomicAdd(ws + WS_LOSS, lsum);
  atomicAdd(ws + WS_HDR + K + bk, 1.0f);

  __syncthreads();
  const int wv = tid >> 6, lane = tid & 63;
  float* emb = ws + WS_HDR + 2 * K;
  for (int rr = 0; rr < 64; ++rr) {       // coalesced: 64 lanes hit one emb row
    const int lr = wv * 64 + rr;
    const u32 b2 = bkb[lr];
    atomicAdd(emb + ((size_t)b2 << 6) + lane, zt[lr * 65 + lane]);
  }
}

__global__ __launch_bounds__(256) void k_fin(const float* __restrict__ ecs,
                                             const float* __restrict__ ees,
                                             const float* __restrict__ ws,
                                             float* __restrict__ o,
                                             int N, int K, float lossmul) {
  const int KD = K << 6;
  const int idx = blockIdx.x * 256 + threadIdx.x;
  if (idx >= KD) return;
  const int k = idx >> 6;
  const int j = idx & 63;
  const size_t base = (size_t)N << 6;

  const float n = 0.99f * ws[WS_SEMA] + 0.01f * (float)N;
  const float cs_new = 0.99f * ecs[k] + 0.01f * ws[WS_HDR + K + k];
  const float smoothed = (cs_new + 1e-5f) / (n + (float)K * 1e-5f) * n;
  const float es_new = 0.99f * ees[idx] + 0.01f * ws[WS_HDR + 2 * K + idx];

  const size_t es_base = base + 1 + (size_t)N + (size_t)K;
  o[es_base + (size_t)idx] = es_new;
  o[es_base + (size_t)KD + (size_t)idx] = es_new / smoothed;
  if (j == 0)   o[base + 1 + (size_t)N + (size_t)k] = cs_new;
  if (idx == 0) o[base] = ws[WS_LOSS] * lossmul;
}

extern "C" void kernel_launch(void* const* d_in, const int* in_sizes, int n_in,
                              void* d_out, int out_size, void* d_ws, size_t ws_size,
                              hipStream_t stream) {
  float* o = (float*)d_out;
  const float* z   = (const float*)d_in[0];
  const float* cb  = (const float*)d_in[1];
  const float* ecs = (const float*)d_in[2];
  const float* ees = (const float*)d_in[3];
  float* ws = (float*)d_ws;

  const long long ND  = (n_in > 0) ? (long long)in_sizes[0] : 0;
  const long long KD  = (n_in > 1) ? (long long)in_sizes[1] : 0;
  const long long K   = (n_in > 2) ? (long long)in_sizes[2] : 0;
  const long long KD2 = (n_in > 3) ? (long long)in_sizes[3] : 0;
  const long long D   = (K > 0) ? KD / K : 0;
  const long long N   = (D > 0) ? ND / D : 0;
  const long long ws_floats = 16 + 2 * K + KD + N;   // + win u32[N]

  float sig = 0.f;
  if (n_in != 4)                          sig = 1e4f * (float)n_in;
  else if (K <= 0 || KD % K != 0)         sig = 2.5e7f;
  else if (D != 64)                       sig = 1e7f + 1e4f * (float)D;
  else if (KD2 != KD)                     sig = 2e7f;
  else if (ND % 64 != 0 || N % 256 != 0)  sig = 3e7f;
  else if (K % 256 != 0)                  sig = 5e7f;
  else if ((long long)out_size != ND + 1 + N + K + 2 * KD)
                                          sig = (float)out_size;
  else if (ws_size < (size_t)ws_floats * sizeof(float))
                                          sig = 7e6f;
  if (sig != 0.f) { k_sig<<<1, 1, 0, stream>>>(o, sig); return; }

  u32* win = (u32*)(ws + 16 + 2 * K + KD);
  // esplit scratch lives in d_out's es/cb tail (k_fin overwrites it last)
  const long long espoff = (ND + 1 + N + K + 3) & ~3LL;    // 16B-align
  uint4* esp = (uint4*)(o + espoff);
  const float lossmul = (float)(0.25 / (double)ND);

  hipMemsetAsync(ws, 0, (size_t)(16 + 2 * K + KD) * sizeof(float), stream);
  k_prep  <<<(int)(K / 256), 256, 0, stream>>>(cb, ecs, ws, (int)K);
  k_esplit<<<(int)(K / 32), 256, 0, stream>>>(cb, esp);
  k_main  <<<(int)(N / 64), 256, 0, stream>>>(z, esp, ws + WS_HDR, win, (int)N, (int)K);
  k_clean <<<(int)(N / 64), 256, 0, stream>>>(z, cb, ws + WS_HDR, win, (int)N, (int)K);
  k_post  <<<(int)(N / 256), 256, 0, stream>>>(z, cb, win, ws, o, (int)N, (int)K);
  k_fin   <<<(int)(KD / 256), 256, 0, stream>>>(ecs, ees, ws, o, (int)N, (int)K, lossmul);
}